// Round 3
// baseline (1569.674 us; speedup 1.0000x reference)
//
#include <hip/hip_runtime.h>
#include <math.h>

#define BB 4
#define TT 10
#define HH 96
#define WW 96
#define HWSZ 9216
#define LL 5

typedef _Float16 half8 __attribute__((ext_vector_type(8)));
typedef _Float16 half4 __attribute__((ext_vector_type(4)));
typedef float floatx4 __attribute__((ext_vector_type(4)));

// ---------------- prep: weights -> f16, MFMA-friendly [co][k] layouts ----------------
// wi16/wh16: [co=32][k=1600], k = tap*64 + ci   (tap = ky*5+kx)
// wA16:      [co=192][k=576], k = tap*64 + ci   (tap = ky*3+kx)
// rw16:      [co=192][k=320], k = l*64 + c
// fw16:      [co=16(10 live)][k=800], k = tap*32 + ci
__global__ __launch_bounds__(256) void prep_weights(const float* __restrict__ i2f_w,
                                                    const float* __restrict__ h2f_w,
                                                    const float* __restrict__ i2h_w,
                                                    const float* __restrict__ ret_w,
                                                    const float* __restrict__ flows_w,
                                                    _Float16* __restrict__ wi16,
                                                    _Float16* __restrict__ wh16,
                                                    _Float16* __restrict__ wA16,
                                                    _Float16* __restrict__ rw16,
                                                    _Float16* __restrict__ fw16) {
    const int id = blockIdx.x * 256 + threadIdx.x;   // 0..287231
    if (id < 51200) {
        const int co = id / 1600, k = id % 1600, tap = k >> 6, ci = k & 63;
        wi16[id] = (_Float16)i2f_w[(co * 64 + ci) * 25 + tap];
    } else if (id < 102400) {
        const int r = id - 51200;
        const int co = r / 1600, k = r % 1600, tap = k >> 6, ci = k & 63;
        wh16[r] = (_Float16)h2f_w[(co * 64 + ci) * 25 + tap];
    } else if (id < 212992) {
        const int r = id - 102400;
        const int co = r / 576, k = r % 576, tap = k >> 6, ci = k & 63;
        wA16[r] = (_Float16)i2h_w[(co * 64 + ci) * 9 + tap];
    } else if (id < 274432) {
        const int r = id - 212992;
        rw16[r] = (_Float16)ret_w[r];   // already [co][320] with k = l*64+c
    } else {
        const int r = id - 274432;      // 0..12799
        const int co = r / 800, k = r % 800, tap = k >> 5, ci = k & 31;
        fw16[r] = (co < 10) ? (_Float16)flows_w[(co * 32 + ci) * 25 + tap] : (_Float16)0.0f;
    }
}

// ---------------- prep: x -> f16 channel-last x16[img][pos][ci], img flat (b*TT+t) ----
__global__ __launch_bounds__(256) void prep_x16(const float* __restrict__ x,
                                                _Float16* __restrict__ x16) {
    const int id = blockIdx.x * 256 + threadIdx.x;   // 0..368639
    const int img = id / HWSZ, pos = id % HWSZ;
    const float* src = x + (size_t)img * 64 * HWSZ + pos;
    _Float16* dst = x16 + ((size_t)img * HWSZ + pos) * 64;
    #pragma unroll
    for (int i = 0; i < 8; i++) {
        half8 v;
        #pragma unroll
        for (int j = 0; j < 8; j++)
            v[j] = (_Float16)src[(size_t)(i * 8 + j) * HWSZ];
        *(half8*)(dst + i * 8) = v;
    }
}

// ---------------- f1x: conv5x5(x_t) partial sums for ALL t, f32 out -------------------
// Grid 40*144 = 5760. g = t*4+b; src image = inputs[b,t] (natural). 16x4 tile.
// 4-wave split: (tap-half, ci-half); LDS reduce; wave0 stores raw f32 partial (no bias).
__global__ __launch_bounds__(256) void f1x_all(const _Float16* __restrict__ x16,
                                               const _Float16* __restrict__ wi16,
                                               float* __restrict__ f1x) {
    __shared__ __align__(16) char smraw[25344];     // max(patch 20480, red 25344)
    _Float16* patch = (_Float16*)smraw;
    float* red = (float*)smraw;
    const int tid = threadIdx.x;
    const int wv = tid >> 6, ln = tid & 63;
    const int lm = ln & 15, q = ln >> 4;
    const int g  = blockIdx.x / 144;                // t*4+b
    const int ti = blockIdx.x % 144;
    const int y0 = (ti / 6) * 4, x0 = (ti % 6) * 16;
    const int tt = g >> 2, b = g & 3;
    const _Float16* src = x16 + (size_t)(b * TT + tt) * HWSZ * 64;

    // stage 8x20 patch (rows y0-2..y0+5, cols x0-2..x0+17), swizzled
    for (int m = tid; m < 1280; m += 256) {
        const int p = m >> 3, c = m & 7;
        const int pr = p / 20, pc = p % 20;
        const int gy = y0 - 2 + pr, gx = x0 - 2 + pc;
        half8 v = {};
        if (gy >= 0 && gy < HH && gx >= 0 && gx < WW)
            v = *(const half8*)(src + (size_t)(gy * WW + gx) * 64 + c * 8);
        *(half8*)(&patch[p * 64 + ((c * 8) ^ ((p & 7) << 3))]) = v;
    }
    __syncthreads();

    const int ci0 = (wv & 1) * 32;
    const int tp0 = (wv >> 1) ? 13 : 0, tp1 = (wv >> 1) ? 25 : 13;
    floatx4 acc[4][2] = {};
    for (int tap = tp0; tap < tp1; tap++) {
        const int ky = tap / 5, kx = tap % 5;
        const half8 a0 = *(const half8*)(wi16 + (size_t)(0 * 16 + lm) * 1600 + tap * 64 + ci0 + q * 8);
        const half8 a1 = *(const half8*)(wi16 + (size_t)(1 * 16 + lm) * 1600 + tap * 64 + ci0 + q * 8);
        #pragma unroll
        for (int n = 0; n < 4; n++) {
            const int p = (n + ky) * 20 + lm + kx;
            const half8 bf = *(const half8*)(&patch[p * 64 + ((ci0 + q * 8) ^ ((p & 7) << 3))]);
            acc[n][0] = __builtin_amdgcn_mfma_f32_16x16x32_f16(a0, bf, acc[n][0], 0, 0, 0);
            acc[n][1] = __builtin_amdgcn_mfma_f32_16x16x32_f16(a1, bf, acc[n][1], 0, 0, 0);
        }
    }
    __syncthreads();
    if (wv) {
        #pragma unroll
        for (int n = 0; n < 4; n++)
            #pragma unroll
            for (int mt = 0; mt < 2; mt++)
                #pragma unroll
                for (int r = 0; r < 4; r++)
                    red[((wv - 1) * 64 + ln) * 33 + n * 8 + mt * 4 + r] = acc[n][mt][r];
    }
    __syncthreads();
    if (wv == 0) {
        #pragma unroll
        for (int w = 0; w < 3; w++)
            #pragma unroll
            for (int n = 0; n < 4; n++)
                #pragma unroll
                for (int mt = 0; mt < 2; mt++)
                    #pragma unroll
                    for (int r = 0; r < 4; r++)
                        acc[n][mt][r] += red[(w * 64 + ln) * 33 + n * 8 + mt * 4 + r];
        #pragma unroll
        for (int n = 0; n < 4; n++) {
            const int pos = (y0 + n) * WW + x0 + lm;
            float* op = f1x + ((size_t)g * HWSZ + pos) * 32;
            #pragma unroll
            for (int mt = 0; mt < 2; mt++)
                *(floatx4*)(op + mt * 16 + q * 4) = acc[n][mt];
        }
    }
}

// ---------------- f1h: tanh(conv5x5(h) + f1x + biases), 16x2 tile, grid 1152 ----------
__global__ __launch_bounds__(256) void f1h_mfma(const _Float16* __restrict__ h16p,
                                                const _Float16* __restrict__ wh16,
                                                const float* __restrict__ f1x,
                                                const float* __restrict__ bi,
                                                const float* __restrict__ bh,
                                                _Float16* __restrict__ f116, int t) {
    __shared__ __align__(16) char smraw[15360];     // max(patch 15360, red 13056)
    _Float16* patch = (_Float16*)smraw;
    float* red = (float*)smraw;
    const int tid = threadIdx.x;
    const int wv = tid >> 6, ln = tid & 63;
    const int lm = ln & 15, q = ln >> 4;
    const int b  = blockIdx.x / 288;
    const int ti = blockIdx.x % 288;
    const int y0 = (ti / 6) * 2, x0 = (ti % 6) * 16;
    const _Float16* src = h16p + (size_t)b * HWSZ * 64;

    // stage 6x20 patch (rows y0-2..y0+3, cols x0-2..x0+17)
    for (int m = tid; m < 960; m += 256) {
        const int p = m >> 3, c = m & 7;
        const int pr = p / 20, pc = p % 20;
        const int gy = y0 - 2 + pr, gx = x0 - 2 + pc;
        half8 v = {};
        if (gy >= 0 && gy < HH && gx >= 0 && gx < WW)
            v = *(const half8*)(src + (size_t)(gy * WW + gx) * 64 + c * 8);
        *(half8*)(&patch[p * 64 + ((c * 8) ^ ((p & 7) << 3))]) = v;
    }
    __syncthreads();

    const int ci0 = (wv & 1) * 32;
    const int tp0 = (wv >> 1) ? 13 : 0, tp1 = (wv >> 1) ? 25 : 13;
    floatx4 acc[2][2] = {};
    for (int tap = tp0; tap < tp1; tap++) {
        const int ky = tap / 5, kx = tap % 5;
        const half8 a0 = *(const half8*)(wh16 + (size_t)(0 * 16 + lm) * 1600 + tap * 64 + ci0 + q * 8);
        const half8 a1 = *(const half8*)(wh16 + (size_t)(1 * 16 + lm) * 1600 + tap * 64 + ci0 + q * 8);
        #pragma unroll
        for (int n = 0; n < 2; n++) {
            const int p = (n + ky) * 20 + lm + kx;
            const half8 bf = *(const half8*)(&patch[p * 64 + ((ci0 + q * 8) ^ ((p & 7) << 3))]);
            acc[n][0] = __builtin_amdgcn_mfma_f32_16x16x32_f16(a0, bf, acc[n][0], 0, 0, 0);
            acc[n][1] = __builtin_amdgcn_mfma_f32_16x16x32_f16(a1, bf, acc[n][1], 0, 0, 0);
        }
    }
    __syncthreads();
    if (wv) {
        #pragma unroll
        for (int n = 0; n < 2; n++)
            #pragma unroll
            for (int mt = 0; mt < 2; mt++)
                #pragma unroll
                for (int r = 0; r < 4; r++)
                    red[((wv - 1) * 64 + ln) * 17 + n * 8 + mt * 4 + r] = acc[n][mt][r];
    }
    __syncthreads();
    if (wv == 0) {
        #pragma unroll
        for (int w = 0; w < 3; w++)
            #pragma unroll
            for (int n = 0; n < 2; n++)
                #pragma unroll
                for (int mt = 0; mt < 2; mt++)
                    #pragma unroll
                    for (int r = 0; r < 4; r++)
                        acc[n][mt][r] += red[(w * 64 + ln) * 17 + n * 8 + mt * 4 + r];
        const int bb = blockIdx.x / 288;
        #pragma unroll
        for (int n = 0; n < 2; n++) {
            const int pos = (y0 + n) * WW + x0 + lm;
            const float* vx = f1x + ((size_t)(t * BB + bb) * HWSZ + pos) * 32;
            _Float16* op = f116 + ((size_t)bb * HWSZ + pos) * 32;
            #pragma unroll
            for (int mt = 0; mt < 2; mt++) {
                const floatx4 xv = *(const floatx4*)(vx + mt * 16 + q * 4);
                half4 pk;
                #pragma unroll
                for (int r = 0; r < 4; r++)
                    pk[r] = (_Float16)tanhf(acc[n][mt][r] + xv[r]
                                            + bi[mt * 16 + q * 4 + r]
                                            + bh[mt * 16 + q * 4 + r]);
                *(half4*)(op + mt * 16 + q * 4) = pk;
            }
        }
    }
}

// ---------------- flows: conv5x5(f1,32->10), one BLOCK per n-tile, 4-way tap-split ----
__global__ __launch_bounds__(256) void flows_mfma(const _Float16* __restrict__ f116,
                                                  const _Float16* __restrict__ fw16,
                                                  const float* __restrict__ bias,
                                                  float* __restrict__ out) {
    __shared__ float red[3][64][4];
    const int wv = threadIdx.x >> 6;
    const int ln = threadIdx.x & 63;
    const int lm = ln & 15, q = ln >> 4;
    const int nt = blockIdx.x;                   // 0..2303
    const int b  = nt / 576;
    const int ti = nt % 576;
    const int y  = ti / 6, xx = (ti % 6) * 16;

    floatx4 acc = {};
    const _Float16* fb = f116 + (size_t)b * HWSZ * 32;
    const int t0 = (25 * wv) / 4, t1 = (25 * (wv + 1)) / 4;   // 6/6/6/7 taps
    for (int tap = t0; tap < t1; tap++) {
        const int ky = tap / 5 - 2, kx = tap % 5 - 2;
        const int gy = y + ky, gx = xx + lm + kx;
        half8 bf = {};
        if (gy >= 0 && gy < HH && gx >= 0 && gx < WW)
            bf = *(const half8*)(fb + (size_t)(gy * WW + gx) * 32 + q * 8);
        const half8 af = *(const half8*)(fw16 + (size_t)lm * 800 + tap * 32 + q * 8);
        acc = __builtin_amdgcn_mfma_f32_16x16x32_f16(af, bf, acc, 0, 0, 0);
    }
    if (wv) {
        #pragma unroll
        for (int r = 0; r < 4; r++) red[wv - 1][ln][r] = acc[r];
    }
    __syncthreads();
    if (wv == 0) {
        #pragma unroll
        for (int w = 0; w < 3; w++)
            #pragma unroll
            for (int r = 0; r < 4; r++) acc[r] += red[w][ln][r];
        const int pos = y * WW + xx + lm;
        #pragma unroll
        for (int r = 0; r < 4; r++) {
            const int c = q * 4 + r;
            if (c < 10)
                out[((size_t)b * 10 + c) * HWSZ + pos] = acc[r] + bias[c];
        }
    }
}

// ---------------- gate_mega: warp-gather + i2h(3x3) + h2h(1x1) + GRU gates ------------
// Grid 2304; block = 16x1 strip (b, row y, cols x0..x0+15).
// Phase 1: stage 3x18 x-patch (image t*4+b), bilinear weights for 80 (pos,l) pairs.
// Phase 2: gather warped tile [16][320] f16 into LDS from h16p.
// Phase 3: wave wv accumulates m-tiles {wv,wv+4,wv+8} = (r,u,m) chans 16wv..16wv+15:
//          r,u accumulators merged (i2h+h2h added in ref); m kept separate (r*h2h_m).
__global__ __launch_bounds__(256) void gate_mega(const _Float16* __restrict__ x16,
                                                 const _Float16* __restrict__ wA16,
                                                 const float* __restrict__ i2h_b,
                                                 const _Float16* __restrict__ h16p,
                                                 const float* __restrict__ flows,
                                                 const _Float16* __restrict__ rw16,
                                                 const float* __restrict__ ret_b,
                                                 float* __restrict__ outs,
                                                 float* __restrict__ last_h,
                                                 _Float16* __restrict__ h16c, int t) {
    __shared__ _Float16 xp[54 * 64];                // 6912 B, 3x18 patch
    __shared__ _Float16 wp[16 * 320];               // 10240 B, warped tile
    __shared__ int   goff[80][4];
    __shared__ float gwgt[80][4];
    const int tid = threadIdx.x;
    const int wv = tid >> 6, ln = tid & 63;
    const int lm = ln & 15, q = ln >> 4;
    const int b  = blockIdx.x / 576;
    const int ti = blockIdx.x % 576;
    const int y  = ti / 6, x0 = (ti % 6) * 16;

    // phase 1a: x patch rows y-1..y+1, cols x0-1..x0+16 (image remap quirk: q=t*4+b)
    const _Float16* xb = x16 + (size_t)(t * BB + b) * HWSZ * 64;
    for (int m = tid; m < 432; m += 256) {
        const int p = m >> 3, c = m & 7;
        const int pr = p / 18, pc = p % 18;
        const int gy = y - 1 + pr, gx = x0 - 1 + pc;
        half8 v = {};
        if (gy >= 0 && gy < HH && gx >= 0 && gx < WW)
            v = *(const half8*)(xb + (size_t)(gy * WW + gx) * 64 + c * 8);
        *(half8*)(&xp[p * 64 + ((c * 8) ^ ((p & 7) << 3))]) = v;
    }
    // phase 1b: bilinear offsets/weights per (pos,l)
    if (tid < 80) {
        const int pp = tid / 5, l = tid % 5;
        const int p = y * WW + x0 + pp;
        const float f0  = -flows[((size_t)b * 10 + l * 2 + 0) * HWSZ + p];
        const float f1v = -flows[((size_t)b * 10 + l * 2 + 1) * HWSZ + p];
        const float nx = 2.0f * ((float)(x0 + pp) + f0)  / (float)(WW - 1) - 1.0f;
        const float ny = 2.0f * ((float)y + f1v) / (float)(HH - 1) - 1.0f;
        const float fx = (nx + 1.0f) * (WW * 0.5f) - 0.5f;
        const float fy = (ny + 1.0f) * (HH * 0.5f) - 0.5f;
        const float x0f = floorf(fx), y0f = floorf(fy);
        const float wx = fx - x0f, wy = fy - y0f;
        const int xi0 = (int)x0f, yi0 = (int)y0f;
        #pragma unroll
        for (int k = 0; k < 4; k++) {
            const int yi = yi0 + (k >> 1);
            const int xi = xi0 + (k & 1);
            const bool ok = (xi >= 0 && xi < WW && yi >= 0 && yi < HH);
            const int yc = min(max(yi, 0), HH - 1);
            const int xc = min(max(xi, 0), WW - 1);
            goff[tid][k] = yc * WW + xc;
            const float wk = ((k & 1) ? wx : 1.0f - wx) * ((k >> 1) ? wy : 1.0f - wy);
            gwgt[tid][k] = ok ? wk : 0.0f;
        }
    }
    __syncthreads();

    // phase 2: gather warped tile [pos][l*64+ch] into LDS (swizzled by pos&7)
    const _Float16* hb = h16p + (size_t)b * HWSZ * 64;
    for (int m = tid; m < 640; m += 256) {
        const int pl = m >> 3, c = m & 7;
        const int pp = pl / 5, l = pl % 5;
        const half8 v0 = *(const half8*)(hb + (size_t)goff[pl][0] * 64 + c * 8);
        const half8 v1 = *(const half8*)(hb + (size_t)goff[pl][1] * 64 + c * 8);
        const half8 v2 = *(const half8*)(hb + (size_t)goff[pl][2] * 64 + c * 8);
        const half8 v3 = *(const half8*)(hb + (size_t)goff[pl][3] * 64 + c * 8);
        const float w0 = gwgt[pl][0], w1 = gwgt[pl][1], w2 = gwgt[pl][2], w3 = gwgt[pl][3];
        half8 o;
        #pragma unroll
        for (int j = 0; j < 8; j++)
            o[j] = (_Float16)((float)v0[j] * w0 + (float)v1[j] * w1
                            + (float)v2[j] * w2 + (float)v3[j] * w3);
        *(half8*)(&wp[pp * 320 + ((l * 64 + c * 8) ^ ((pp & 7) << 3))]) = o;
    }
    __syncthreads();

    // phase 3: MFMA. accR/accU merged (i2h + h2h + both biases); accIM/accHM separate.
    floatx4 accR, accU, accIM, accHM;
    #pragma unroll
    for (int r = 0; r < 4; r++) {
        const int c = wv * 16 + q * 4 + r;
        accR[r]  = i2h_b[c]        + ret_b[c];
        accU[r]  = i2h_b[64 + c]   + ret_b[64 + c];
        accIM[r] = i2h_b[128 + c];
        accHM[r] = ret_b[128 + c];
    }
    // i2h 3x3 taps from x patch
    for (int tap = 0; tap < 9; tap++) {
        const int ky = tap / 3, kx = tap % 3;
        const int p = ky * 18 + lm + kx;
        const int sw = (p & 7) << 3;
        const half8 bf0 = *(const half8*)(&xp[p * 64 + ((q * 8) ^ sw)]);
        const half8 bf1 = *(const half8*)(&xp[p * 64 + ((32 + q * 8) ^ sw)]);
        #pragma unroll
        for (int h = 0; h < 2; h++) {
            const half8 bf = h ? bf1 : bf0;
            const int k0 = tap * 64 + h * 32;
            const half8 ar = *(const half8*)(wA16 + (size_t)((wv + 0) * 16 + lm) * 576 + k0 + q * 8);
            const half8 au = *(const half8*)(wA16 + (size_t)((wv + 4) * 16 + lm) * 576 + k0 + q * 8);
            const half8 am = *(const half8*)(wA16 + (size_t)((wv + 8) * 16 + lm) * 576 + k0 + q * 8);
            accR  = __builtin_amdgcn_mfma_f32_16x16x32_f16(ar, bf, accR,  0, 0, 0);
            accU  = __builtin_amdgcn_mfma_f32_16x16x32_f16(au, bf, accU,  0, 0, 0);
            accIM = __builtin_amdgcn_mfma_f32_16x16x32_f16(am, bf, accIM, 0, 0, 0);
        }
    }
    // h2h 1x1 (K=320) from warped LDS tile
    for (int s = 0; s < 10; s++) {
        const half8 bf = *(const half8*)(&wp[lm * 320 + ((s * 32 + q * 8) ^ ((lm & 7) << 3))]);
        const int k0 = s * 32;
        const half8 ar = *(const half8*)(rw16 + (size_t)((wv + 0) * 16 + lm) * 320 + k0 + q * 8);
        const half8 au = *(const half8*)(rw16 + (size_t)((wv + 4) * 16 + lm) * 320 + k0 + q * 8);
        const half8 am = *(const half8*)(rw16 + (size_t)((wv + 8) * 16 + lm) * 320 + k0 + q * 8);
        accR  = __builtin_amdgcn_mfma_f32_16x16x32_f16(ar, bf, accR,  0, 0, 0);
        accU  = __builtin_amdgcn_mfma_f32_16x16x32_f16(au, bf, accU,  0, 0, 0);
        accHM = __builtin_amdgcn_mfma_f32_16x16x32_f16(am, bf, accHM, 0, 0, 0);
    }

    // epilogue: GRU gates; prev h read from outs[t-1] (f32), zeros at t=0
    const int pos = y * WW + x0 + lm;
    half4 pk;
    #pragma unroll
    for (int r = 0; r < 4; r++) {
        const int c = wv * 16 + q * 4 + r;
        const float rg = 1.0f / (1.0f + expf(-accR[r]));
        const float ug = 1.0f / (1.0f + expf(-accU[r]));
        const float mg = tanhf(accIM[r] + rg * accHM[r]);
        const float hp = (t > 0) ? outs[(((size_t)b * TT + (t - 1)) * 64 + c) * HWSZ + pos] : 0.0f;
        const float nh = ug * hp + (1.0f - ug) * mg;
        outs[(((size_t)b * TT + t) * 64 + c) * HWSZ + pos] = nh;
        if (t == TT - 1) last_h[((size_t)b * 64 + c) * HWSZ + pos] = nh;
        pk[r] = (_Float16)nh;
    }
    *(half4*)(h16c + ((size_t)b * HWSZ + pos) * 64 + wv * 16 + q * 4) = pk;
}

extern "C" void kernel_launch(void* const* d_in, const int* in_sizes, int n_in,
                              void* d_out, int out_size, void* d_ws, size_t ws_size,
                              hipStream_t stream) {
    const float* inputs  = (const float*)d_in[0];
    const float* i2h_w   = (const float*)d_in[1];
    const float* i2h_b   = (const float*)d_in[2];
    const float* i2f_w   = (const float*)d_in[3];
    const float* i2f_b   = (const float*)d_in[4];
    const float* h2f_w   = (const float*)d_in[5];
    const float* h2f_b   = (const float*)d_in[6];
    const float* flows_w = (const float*)d_in[7];
    const float* flows_b = (const float*)d_in[8];
    const float* ret_w   = (const float*)d_in[9];
    const float* ret_b   = (const float*)d_in[10];

    float* out = (float*)d_out;

    // workspace layout (bytes), total ~108.2 MB
    char* base = (char*)d_ws;
    _Float16* h16    = (_Float16*)base;   base += 9437184;    // 2 x (4*9216*64) f16 dbuf
    _Float16* f116   = (_Float16*)base;   base += 2359296;    // 4*9216*32 f16
    float*    flowsb = (float*)base;      base += 1474560;    // 4*10*9216 f32
    _Float16* x16    = (_Float16*)base;   base += 47185920;   // 40*9216*64 f16
    float*    f1x    = (float*)base;      base += 47185920;   // 40*9216*32 f32
    _Float16* wi16   = (_Float16*)base;   base += 102400;     // 32*1600
    _Float16* wh16   = (_Float16*)base;   base += 102400;
    _Float16* wA16   = (_Float16*)base;   base += 221184;     // 192*576
    _Float16* rw16   = (_Float16*)base;   base += 122880;     // 192*320
    _Float16* fw16   = (_Float16*)base;   base += 25600;      // 16*800

    float* outs   = out;
    float* last_h = out + (size_t)BB * TT * 64 * HWSZ;

    hipMemsetAsync(h16, 0, 4718592, stream);   // buffer 0 = h at t=0

    prep_weights<<<1122, 256, 0, stream>>>(i2f_w, h2f_w, i2h_w, ret_w, flows_w,
                                           wi16, wh16, wA16, rw16, fw16);
    prep_x16<<<1440, 256, 0, stream>>>(inputs, x16);
    f1x_all<<<5760, 256, 0, stream>>>(x16, wi16, f1x);

    const size_t HB = (size_t)BB * HWSZ * 64;   // elements per h16 buffer
    for (int t = 0; t < TT; t++) {
        _Float16* hprev = h16 + (size_t)(t & 1) * HB;
        _Float16* hcur  = h16 + (size_t)((t + 1) & 1) * HB;
        f1h_mfma<<<1152, 256, 0, stream>>>(hprev, wh16, f1x, i2f_b, h2f_b, f116, t);
        flows_mfma<<<2304, 256, 0, stream>>>(f116, fw16, flows_b, flowsb);
        gate_mega<<<2304, 256, 0, stream>>>(x16, wA16, i2h_b, hprev, flowsb, rw16, ret_b,
                                            outs, last_h, hcur, t);
    }
}

// Round 4
// 1090.372 us; speedup vs baseline: 1.4396x; 1.4396x over previous
//
#include <hip/hip_runtime.h>
#include <math.h>

#define BB 4
#define TT 10
#define HH 96
#define WW 96
#define HWSZ 9216
#define LL 5

typedef _Float16 half8 __attribute__((ext_vector_type(8)));
typedef _Float16 half4 __attribute__((ext_vector_type(4)));
typedef float floatx4 __attribute__((ext_vector_type(4)));

// ---------------- prep: weights -> f16, MFMA-friendly [co][k] layouts ----------------
__global__ __launch_bounds__(256) void prep_weights(const float* __restrict__ i2f_w,
                                                    const float* __restrict__ h2f_w,
                                                    const float* __restrict__ i2h_w,
                                                    const float* __restrict__ ret_w,
                                                    const float* __restrict__ flows_w,
                                                    _Float16* __restrict__ wi16,
                                                    _Float16* __restrict__ wh16,
                                                    _Float16* __restrict__ wA16,
                                                    _Float16* __restrict__ rw16,
                                                    _Float16* __restrict__ fw16) {
    const int id = blockIdx.x * 256 + threadIdx.x;   // 0..287231
    if (id < 51200) {
        const int co = id / 1600, k = id % 1600, tap = k >> 6, ci = k & 63;
        wi16[id] = (_Float16)i2f_w[(co * 64 + ci) * 25 + tap];
    } else if (id < 102400) {
        const int r = id - 51200;
        const int co = r / 1600, k = r % 1600, tap = k >> 6, ci = k & 63;
        wh16[r] = (_Float16)h2f_w[(co * 64 + ci) * 25 + tap];
    } else if (id < 212992) {
        const int r = id - 102400;
        const int co = r / 576, k = r % 576, tap = k >> 6, ci = k & 63;
        wA16[r] = (_Float16)i2h_w[(co * 64 + ci) * 9 + tap];
    } else if (id < 274432) {
        const int r = id - 212992;
        rw16[r] = (_Float16)ret_w[r];   // already [co][320] with k = l*64+c
    } else {
        const int r = id - 274432;      // 0..12799
        const int co = r / 800, k = r % 800, tap = k >> 5, ci = k & 31;
        fw16[r] = (co < 10) ? (_Float16)flows_w[(co * 32 + ci) * 25 + tap] : (_Float16)0.0f;
    }
}

// ---------------- prep: x -> f16 channel-last x16[img][pos][ci], img flat (b*TT+t) ----
__global__ __launch_bounds__(256) void prep_x16(const float* __restrict__ x,
                                                _Float16* __restrict__ x16) {
    const int id = blockIdx.x * 256 + threadIdx.x;   // 0..368639
    const int img = id / HWSZ, pos = id % HWSZ;
    const float* src = x + (size_t)img * 64 * HWSZ + pos;
    _Float16* dst = x16 + ((size_t)img * HWSZ + pos) * 64;
    #pragma unroll
    for (int i = 0; i < 8; i++) {
        half8 v;
        #pragma unroll
        for (int j = 0; j < 8; j++)
            v[j] = (_Float16)src[(size_t)(i * 8 + j) * HWSZ];
        *(half8*)(dst + i * 8) = v;
    }
}

// ---------------- f1x: conv5x5(x_t) partial sums for ALL t, f32 out -------------------
__global__ __launch_bounds__(256) void f1x_all(const _Float16* __restrict__ x16,
                                               const _Float16* __restrict__ wi16,
                                               float* __restrict__ f1x) {
    __shared__ __align__(16) char smraw[25344];     // max(patch 20480, red 25344)
    _Float16* patch = (_Float16*)smraw;
    float* red = (float*)smraw;
    const int tid = threadIdx.x;
    const int wv = tid >> 6, ln = tid & 63;
    const int lm = ln & 15, q = ln >> 4;
    const int g  = blockIdx.x / 144;                // t*4+b
    const int ti = blockIdx.x % 144;
    const int y0 = (ti / 6) * 4, x0 = (ti % 6) * 16;
    const int tt = g >> 2, b = g & 3;
    const _Float16* src = x16 + (size_t)(b * TT + tt) * HWSZ * 64;

    for (int m = tid; m < 1280; m += 256) {
        const int p = m >> 3, c = m & 7;
        const int pr = p / 20, pc = p % 20;
        const int gy = y0 - 2 + pr, gx = x0 - 2 + pc;
        half8 v = {};
        if (gy >= 0 && gy < HH && gx >= 0 && gx < WW)
            v = *(const half8*)(src + (size_t)(gy * WW + gx) * 64 + c * 8);
        *(half8*)(&patch[p * 64 + ((c * 8) ^ ((p & 7) << 3))]) = v;
    }
    __syncthreads();

    const int ci0 = (wv & 1) * 32;
    const int tp0 = (wv >> 1) ? 13 : 0, tp1 = (wv >> 1) ? 25 : 13;
    floatx4 acc[4][2] = {};
    for (int tap = tp0; tap < tp1; tap++) {
        const int ky = tap / 5, kx = tap % 5;
        const half8 a0 = *(const half8*)(wi16 + (size_t)(0 * 16 + lm) * 1600 + tap * 64 + ci0 + q * 8);
        const half8 a1 = *(const half8*)(wi16 + (size_t)(1 * 16 + lm) * 1600 + tap * 64 + ci0 + q * 8);
        #pragma unroll
        for (int n = 0; n < 4; n++) {
            const int p = (n + ky) * 20 + lm + kx;
            const half8 bf = *(const half8*)(&patch[p * 64 + ((ci0 + q * 8) ^ ((p & 7) << 3))]);
            acc[n][0] = __builtin_amdgcn_mfma_f32_16x16x32_f16(a0, bf, acc[n][0], 0, 0, 0);
            acc[n][1] = __builtin_amdgcn_mfma_f32_16x16x32_f16(a1, bf, acc[n][1], 0, 0, 0);
        }
    }
    __syncthreads();
    if (wv) {
        #pragma unroll
        for (int n = 0; n < 4; n++)
            #pragma unroll
            for (int mt = 0; mt < 2; mt++)
                #pragma unroll
                for (int r = 0; r < 4; r++)
                    red[((wv - 1) * 64 + ln) * 33 + n * 8 + mt * 4 + r] = acc[n][mt][r];
    }
    __syncthreads();
    if (wv == 0) {
        #pragma unroll
        for (int w = 0; w < 3; w++)
            #pragma unroll
            for (int n = 0; n < 4; n++)
                #pragma unroll
                for (int mt = 0; mt < 2; mt++)
                    #pragma unroll
                    for (int r = 0; r < 4; r++)
                        acc[n][mt][r] += red[(w * 64 + ln) * 33 + n * 8 + mt * 4 + r];
        #pragma unroll
        for (int n = 0; n < 4; n++) {
            const int pos = (y0 + n) * WW + x0 + lm;
            float* op = f1x + ((size_t)g * HWSZ + pos) * 32;
            #pragma unroll
            for (int mt = 0; mt < 2; mt++)
                *(floatx4*)(op + mt * 16 + q * 4) = acc[n][mt];
        }
    }
}

// ---------------- f1h: tanh(conv5x5(h) + f1x + biases), 16x2 tile, grid 1152 ----------
__global__ __launch_bounds__(256) void f1h_mfma(const _Float16* __restrict__ h16p,
                                                const _Float16* __restrict__ wh16,
                                                const float* __restrict__ f1x,
                                                const float* __restrict__ bi,
                                                const float* __restrict__ bh,
                                                _Float16* __restrict__ f116, int t) {
    __shared__ __align__(16) char smraw[15360];     // max(patch 15360, red 13056)
    _Float16* patch = (_Float16*)smraw;
    float* red = (float*)smraw;
    const int tid = threadIdx.x;
    const int wv = tid >> 6, ln = tid & 63;
    const int lm = ln & 15, q = ln >> 4;
    const int b  = blockIdx.x / 288;
    const int ti = blockIdx.x % 288;
    const int y0 = (ti / 6) * 2, x0 = (ti % 6) * 16;
    const _Float16* src = h16p + (size_t)b * HWSZ * 64;

    for (int m = tid; m < 960; m += 256) {
        const int p = m >> 3, c = m & 7;
        const int pr = p / 20, pc = p % 20;
        const int gy = y0 - 2 + pr, gx = x0 - 2 + pc;
        half8 v = {};
        if (gy >= 0 && gy < HH && gx >= 0 && gx < WW)
            v = *(const half8*)(src + (size_t)(gy * WW + gx) * 64 + c * 8);
        *(half8*)(&patch[p * 64 + ((c * 8) ^ ((p & 7) << 3))]) = v;
    }
    __syncthreads();

    const int ci0 = (wv & 1) * 32;
    const int tp0 = (wv >> 1) ? 13 : 0, tp1 = (wv >> 1) ? 25 : 13;
    floatx4 acc[2][2] = {};
    for (int tap = tp0; tap < tp1; tap++) {
        const int ky = tap / 5, kx = tap % 5;
        const half8 a0 = *(const half8*)(wh16 + (size_t)(0 * 16 + lm) * 1600 + tap * 64 + ci0 + q * 8);
        const half8 a1 = *(const half8*)(wh16 + (size_t)(1 * 16 + lm) * 1600 + tap * 64 + ci0 + q * 8);
        #pragma unroll
        for (int n = 0; n < 2; n++) {
            const int p = (n + ky) * 20 + lm + kx;
            const half8 bf = *(const half8*)(&patch[p * 64 + ((ci0 + q * 8) ^ ((p & 7) << 3))]);
            acc[n][0] = __builtin_amdgcn_mfma_f32_16x16x32_f16(a0, bf, acc[n][0], 0, 0, 0);
            acc[n][1] = __builtin_amdgcn_mfma_f32_16x16x32_f16(a1, bf, acc[n][1], 0, 0, 0);
        }
    }
    __syncthreads();
    if (wv) {
        #pragma unroll
        for (int n = 0; n < 2; n++)
            #pragma unroll
            for (int mt = 0; mt < 2; mt++)
                #pragma unroll
                for (int r = 0; r < 4; r++)
                    red[((wv - 1) * 64 + ln) * 17 + n * 8 + mt * 4 + r] = acc[n][mt][r];
    }
    __syncthreads();
    if (wv == 0) {
        #pragma unroll
        for (int w = 0; w < 3; w++)
            #pragma unroll
            for (int n = 0; n < 2; n++)
                #pragma unroll
                for (int mt = 0; mt < 2; mt++)
                    #pragma unroll
                    for (int r = 0; r < 4; r++)
                        acc[n][mt][r] += red[(w * 64 + ln) * 17 + n * 8 + mt * 4 + r];
        const int bb = blockIdx.x / 288;
        #pragma unroll
        for (int n = 0; n < 2; n++) {
            const int pos = (y0 + n) * WW + x0 + lm;
            const float* vx = f1x + ((size_t)(t * BB + bb) * HWSZ + pos) * 32;
            _Float16* op = f116 + ((size_t)bb * HWSZ + pos) * 32;
            #pragma unroll
            for (int mt = 0; mt < 2; mt++) {
                const floatx4 xv = *(const floatx4*)(vx + mt * 16 + q * 4);
                half4 pk;
                #pragma unroll
                for (int r = 0; r < 4; r++)
                    pk[r] = (_Float16)tanhf(acc[n][mt][r] + xv[r]
                                            + bi[mt * 16 + q * 4 + r]
                                            + bh[mt * 16 + q * 4 + r]);
                *(half4*)(op + mt * 16 + q * 4) = pk;
            }
        }
    }
}

// ---------------- gate_mega: flows conv + warp-gather + i2h(3x3) + h2h(1x1) + GRU -----
// Grid 768 (= 3/CU exactly); block = 16x3 tile (b, rows y0..y0+2, cols x0..x0+15).
// Phases: stage {x 5x18 patch, f1 7x20 patch} -> flows MFMA (wave rr<3, row rr) ->
//         bilinear coeffs (240 pairs) -> gather warped [48][320] (overwrites f1 patch)
//         -> MFMA: wave wv does gates (r,u,m) = m-tiles {wv,wv+4,wv+8} x 3 rows.
__global__ __launch_bounds__(256) void gate_mega(const _Float16* __restrict__ x16,
                                                 const _Float16* __restrict__ wA16,
                                                 const float* __restrict__ i2h_b,
                                                 const _Float16* __restrict__ h16p,
                                                 const _Float16* __restrict__ f116,
                                                 const _Float16* __restrict__ fw16,
                                                 const float* __restrict__ flows_b,
                                                 const _Float16* __restrict__ rw16,
                                                 const float* __restrict__ ret_b,
                                                 float* __restrict__ outs,
                                                 float* __restrict__ last_h,
                                                 _Float16* __restrict__ h16c, int t) {
    __shared__ _Float16 xp[90 * 64];                // 11520 B, 5x18 x-patch
    __shared__ __align__(16) _Float16 uni[48 * 320];// 30720 B: f1 patch then warped tile
    __shared__ float flw[3][16][5][2];              // 1920 B
    __shared__ int   goff[240][4];                  // 3840 B
    __shared__ float gwgt[240][4];                  // 3840 B
    const int tid = threadIdx.x;
    const int wv = tid >> 6, ln = tid & 63;
    const int lm = ln & 15, q = ln >> 4;
    const int b  = blockIdx.x / 192;
    const int ti = blockIdx.x % 192;
    const int y0 = (ti / 6) * 3, x0 = (ti % 6) * 16;

    // phase 0a: x patch rows y0-1..y0+3, cols x0-1..x0+16 (image remap quirk: t*4+b)
    const _Float16* xb = x16 + (size_t)(t * BB + b) * HWSZ * 64;
    for (int m = tid; m < 720; m += 256) {
        const int p = m >> 3, c = m & 7;
        const int pr = p / 18, pc = p % 18;
        const int gy = y0 - 1 + pr, gx = x0 - 1 + pc;
        half8 v = {};
        if (gy >= 0 && gy < HH && gx >= 0 && gx < WW)
            v = *(const half8*)(xb + (size_t)(gy * WW + gx) * 64 + c * 8);
        *(half8*)(&xp[p * 64 + ((c * 8) ^ ((p & 7) << 3))]) = v;
    }
    // phase 0b: f1 patch rows y0-2..y0+4, cols x0-2..x0+17, stride 40 halfs (pad)
    const _Float16* fb = f116 + (size_t)b * HWSZ * 32;
    for (int m = tid; m < 560; m += 256) {
        const int p = m >> 2, c = m & 3;
        const int pr = p / 20, pc = p % 20;
        const int gy = y0 - 2 + pr, gx = x0 - 2 + pc;
        half8 v = {};
        if (gy >= 0 && gy < HH && gx >= 0 && gx < WW)
            v = *(const half8*)(fb + (size_t)(gy * WW + gx) * 32 + c * 8);
        *(half8*)(&uni[p * 40 + c * 8]) = v;
    }
    __syncthreads();

    // phase 1: flows conv5x5 (M=16, 10 live; K=800). wave rr<3 computes row y0+rr.
    if (wv < 3) {
        floatx4 fa = {};
        for (int tap = 0; tap < 25; tap++) {
            const int ky = tap / 5, kx = tap % 5;
            const half8 af = *(const half8*)(fw16 + (size_t)lm * 800 + tap * 32 + q * 8);
            const int p = (wv + ky) * 20 + lm + kx;
            const half8 bf = *(const half8*)(&uni[p * 40 + q * 8]);
            fa = __builtin_amdgcn_mfma_f32_16x16x32_f16(af, bf, fa, 0, 0, 0);
        }
        #pragma unroll
        for (int r = 0; r < 4; r++) {
            const int c = q * 4 + r;
            if (c < 10)
                flw[wv][lm][c >> 1][c & 1] = fa[r] + flows_b[c];
        }
    }
    __syncthreads();

    // phase 2: bilinear offsets/weights per (pos48, l)
    if (tid < 240) {
        const int pp = tid / 5, l = tid % 5;
        const int rr = pp >> 4, pc = pp & 15;
        const int yg = y0 + rr, xg = x0 + pc;
        const float f0  = -flw[rr][pc][l][0];
        const float f1v = -flw[rr][pc][l][1];
        const float nx = 2.0f * ((float)xg + f0)  / (float)(WW - 1) - 1.0f;
        const float ny = 2.0f * ((float)yg + f1v) / (float)(HH - 1) - 1.0f;
        const float fx = (nx + 1.0f) * (WW * 0.5f) - 0.5f;
        const float fy = (ny + 1.0f) * (HH * 0.5f) - 0.5f;
        const float x0f = floorf(fx), y0f = floorf(fy);
        const float wx = fx - x0f, wy = fy - y0f;
        const int xi0 = (int)x0f, yi0 = (int)y0f;
        #pragma unroll
        for (int k = 0; k < 4; k++) {
            const int yi = yi0 + (k >> 1);
            const int xi = xi0 + (k & 1);
            const bool ok = (xi >= 0 && xi < WW && yi >= 0 && yi < HH);
            const int yc = min(max(yi, 0), HH - 1);
            const int xc = min(max(xi, 0), WW - 1);
            goff[tid][k] = yc * WW + xc;
            const float wk = ((k & 1) ? wx : 1.0f - wx) * ((k >> 1) ? wy : 1.0f - wy);
            gwgt[tid][k] = ok ? wk : 0.0f;
        }
    }
    __syncthreads();

    // phase 3: gather warped tile [pos48][l*64+ch] into uni (f1 patch now dead)
    const _Float16* hb = h16p + (size_t)b * HWSZ * 64;
    for (int m = tid; m < 1920; m += 256) {
        const int pl = m >> 3, c = m & 7;
        const int pp = pl / 5, l = pl % 5;
        const half8 v0 = *(const half8*)(hb + (size_t)goff[pl][0] * 64 + c * 8);
        const half8 v1 = *(const half8*)(hb + (size_t)goff[pl][1] * 64 + c * 8);
        const half8 v2 = *(const half8*)(hb + (size_t)goff[pl][2] * 64 + c * 8);
        const half8 v3 = *(const half8*)(hb + (size_t)goff[pl][3] * 64 + c * 8);
        const float w0 = gwgt[pl][0], w1 = gwgt[pl][1], w2 = gwgt[pl][2], w3 = gwgt[pl][3];
        half8 o;
        #pragma unroll
        for (int j = 0; j < 8; j++)
            o[j] = (_Float16)((float)v0[j] * w0 + (float)v1[j] * w1
                            + (float)v2[j] * w2 + (float)v3[j] * w3);
        *(half8*)(&uni[pp * 320 + ((l * 64 + c * 8) ^ ((pp & 7) << 3))]) = o;
    }
    __syncthreads();

    // phase 4: main MFMA. hp prefetch first (hides HBM latency under MFMAs).
    float hp[3][4];
    #pragma unroll
    for (int nn = 0; nn < 3; nn++) {
        const int pos = (y0 + nn) * WW + x0 + lm;
        #pragma unroll
        for (int r = 0; r < 4; r++) {
            const int c = wv * 16 + q * 4 + r;
            hp[nn][r] = (t > 0) ? outs[(((size_t)b * TT + (t - 1)) * 64 + c) * HWSZ + pos] : 0.0f;
        }
    }

    floatx4 aR[3], aU[3], aIM[3], aHM[3];
    #pragma unroll
    for (int nn = 0; nn < 3; nn++)
        #pragma unroll
        for (int r = 0; r < 4; r++) {
            const int c = wv * 16 + q * 4 + r;
            aR[nn][r]  = i2h_b[c]      + ret_b[c];
            aU[nn][r]  = i2h_b[64 + c] + ret_b[64 + c];
            aIM[nn][r] = i2h_b[128 + c];
            aHM[nn][r] = ret_b[128 + c];
        }

    // i2h 3x3 (K=576) from x patch
    for (int tap = 0; tap < 9; tap++) {
        const int ky = tap / 3, kx = tap % 3;
        #pragma unroll
        for (int h = 0; h < 2; h++) {
            const int k0 = tap * 64 + h * 32;
            const half8 ar = *(const half8*)(wA16 + (size_t)((wv + 0) * 16 + lm) * 576 + k0 + q * 8);
            const half8 au = *(const half8*)(wA16 + (size_t)((wv + 4) * 16 + lm) * 576 + k0 + q * 8);
            const half8 am = *(const half8*)(wA16 + (size_t)((wv + 8) * 16 + lm) * 576 + k0 + q * 8);
            #pragma unroll
            for (int nn = 0; nn < 3; nn++) {
                const int p = (nn + ky) * 18 + lm + kx;
                const int sw = (p & 7) << 3;
                const half8 bf = *(const half8*)(&xp[p * 64 + ((h * 32 + q * 8) ^ sw)]);
                aR[nn]  = __builtin_amdgcn_mfma_f32_16x16x32_f16(ar, bf, aR[nn],  0, 0, 0);
                aU[nn]  = __builtin_amdgcn_mfma_f32_16x16x32_f16(au, bf, aU[nn],  0, 0, 0);
                aIM[nn] = __builtin_amdgcn_mfma_f32_16x16x32_f16(am, bf, aIM[nn], 0, 0, 0);
            }
        }
    }
    // h2h 1x1 (K=320) from warped LDS tile
    for (int s = 0; s < 10; s++) {
        const int k0 = s * 32;
        const half8 ar = *(const half8*)(rw16 + (size_t)((wv + 0) * 16 + lm) * 320 + k0 + q * 8);
        const half8 au = *(const half8*)(rw16 + (size_t)((wv + 4) * 16 + lm) * 320 + k0 + q * 8);
        const half8 am = *(const half8*)(rw16 + (size_t)((wv + 8) * 16 + lm) * 320 + k0 + q * 8);
        #pragma unroll
        for (int nn = 0; nn < 3; nn++) {
            const half8 bf = *(const half8*)(&uni[(nn * 16 + lm) * 320 + ((k0 + q * 8) ^ ((lm & 7) << 3))]);
            aR[nn]  = __builtin_amdgcn_mfma_f32_16x16x32_f16(ar, bf, aR[nn],  0, 0, 0);
            aU[nn]  = __builtin_amdgcn_mfma_f32_16x16x32_f16(au, bf, aU[nn],  0, 0, 0);
            aHM[nn] = __builtin_amdgcn_mfma_f32_16x16x32_f16(am, bf, aHM[nn], 0, 0, 0);
        }
    }

    // epilogue: GRU gates
    #pragma unroll
    for (int nn = 0; nn < 3; nn++) {
        const int pos = (y0 + nn) * WW + x0 + lm;
        half4 pk;
        #pragma unroll
        for (int r = 0; r < 4; r++) {
            const int c = wv * 16 + q * 4 + r;
            const float rg = 1.0f / (1.0f + expf(-aR[nn][r]));
            const float ug = 1.0f / (1.0f + expf(-aU[nn][r]));
            const float mg = tanhf(aIM[nn][r] + rg * aHM[nn][r]);
            const float nh = ug * hp[nn][r] + (1.0f - ug) * mg;
            outs[(((size_t)b * TT + t) * 64 + c) * HWSZ + pos] = nh;
            if (t == TT - 1) last_h[((size_t)b * 64 + c) * HWSZ + pos] = nh;
            pk[r] = (_Float16)nh;
        }
        *(half4*)(h16c + ((size_t)b * HWSZ + pos) * 64 + wv * 16 + q * 4) = pk;
    }
}

extern "C" void kernel_launch(void* const* d_in, const int* in_sizes, int n_in,
                              void* d_out, int out_size, void* d_ws, size_t ws_size,
                              hipStream_t stream) {
    const float* inputs  = (const float*)d_in[0];
    const float* i2h_w   = (const float*)d_in[1];
    const float* i2h_b   = (const float*)d_in[2];
    const float* i2f_w   = (const float*)d_in[3];
    const float* i2f_b   = (const float*)d_in[4];
    const float* h2f_w   = (const float*)d_in[5];
    const float* h2f_b   = (const float*)d_in[6];
    const float* flows_w = (const float*)d_in[7];
    const float* flows_b = (const float*)d_in[8];
    const float* ret_w   = (const float*)d_in[9];
    const float* ret_b   = (const float*)d_in[10];

    float* out = (float*)d_out;

    // workspace layout (bytes), total ~106.8 MB
    char* base = (char*)d_ws;
    _Float16* h16    = (_Float16*)base;   base += 9437184;    // 2 x (4*9216*64) f16 dbuf
    _Float16* f116   = (_Float16*)base;   base += 2359296;    // 4*9216*32 f16
    _Float16* x16    = (_Float16*)base;   base += 47185920;   // 40*9216*64 f16
    float*    f1x    = (float*)base;      base += 47185920;   // 40*9216*32 f32
    _Float16* wi16   = (_Float16*)base;   base += 102400;     // 32*1600
    _Float16* wh16   = (_Float16*)base;   base += 102400;
    _Float16* wA16   = (_Float16*)base;   base += 221184;     // 192*576
    _Float16* rw16   = (_Float16*)base;   base += 122880;     // 192*320
    _Float16* fw16   = (_Float16*)base;   base += 25600;      // 16*800

    float* outs   = out;
    float* last_h = out + (size_t)BB * TT * 64 * HWSZ;

    hipMemsetAsync(h16, 0, 4718592, stream);   // buffer 0 = h at t=0

    prep_weights<<<1122, 256, 0, stream>>>(i2f_w, h2f_w, i2h_w, ret_w, flows_w,
                                           wi16, wh16, wA16, rw16, fw16);
    prep_x16<<<1440, 256, 0, stream>>>(inputs, x16);
    f1x_all<<<5760, 256, 0, stream>>>(x16, wi16, f1x);

    const size_t HB = (size_t)BB * HWSZ * 64;   // elements per h16 buffer
    for (int t = 0; t < TT; t++) {
        _Float16* hprev = h16 + (size_t)(t & 1) * HB;
        _Float16* hcur  = h16 + (size_t)((t + 1) & 1) * HB;
        f1h_mfma<<<1152, 256, 0, stream>>>(hprev, wh16, f1x, i2f_b, h2f_b, f116, t);
        gate_mega<<<768, 256, 0, stream>>>(x16, wA16, i2h_b, hprev, f116, fw16, flows_b,
                                           rw16, ret_b, outs, last_h, hcur, t);
    }
}